// Round 6
// baseline (484.487 us; speedup 1.0000x reference)
//
#include <hip/hip_runtime.h>
#include <hip/hip_bf16.h>
#include <cstddef>

#define BS 8
#define NQ 900
#define DM 256
#define LEN_V 13294

using bf16x8 = __attribute__((ext_vector_type(8))) __bf16;
using f32x4  = __attribute__((ext_vector_type(4))) float;

__device__ __forceinline__ unsigned short f2bf(float f) {
    union { float f; unsigned int u; } v; v.f = f;
    unsigned int r = v.u + 0x7FFFu + ((v.u >> 16) & 1u);
    return (unsigned short)(r >> 16);
}
__device__ __forceinline__ float bf2f(unsigned short u) {
    union { unsigned int u; float f; } v; v.u = ((unsigned int)u) << 16;
    return v.f;
}

#define SW(r) (((r) + ((r) >> 2)) & 3)

// ---------------------------------------------------------------------------
// Batched weight prep: fp32 W[K][N] -> bf16 WT[N][K]
// ---------------------------------------------------------------------------
struct WDesc { const float* src; unsigned short* dst; int K; int N; };
struct WPrepArgs { WDesc w[10]; };

__global__ __launch_bounds__(256) void wprep_kernel(WPrepArgs args)
{
    WDesc d = args.w[blockIdx.z];
    int k0 = blockIdx.x * 32;
    int n0 = blockIdx.y * 32;
    if (k0 >= d.K || n0 >= d.N) return;
    __shared__ unsigned short t[32][33];
    int tx = threadIdx.x & 31, ty = threadIdx.x >> 5;
    #pragma unroll
    for (int i = 0; i < 4; ++i) {
        int kk = ty + i * 8;
        t[kk][tx] = f2bf(d.src[(size_t)(k0 + kk) * d.N + n0 + tx]);
    }
    __syncthreads();
    #pragma unroll
    for (int i = 0; i < 4; ++i) {
        int nn = ty + i * 8;
        d.dst[(size_t)(n0 + nn) * d.K + k0 + tx] = t[tx][nn];
    }
}

// ---------------------------------------------------------------------------
// Full-width bf16 MFMA GEMM: C[M,N] = bf16(A [+A2]) @ B + bias.
// BM=64, BN=256, BK=32; 256 threads = 4 waves, wave tile 64x64 (4x4 frags).
// A fp32 [M][K] converted during staging; BT bf16 [N][K].
// flags: bit0 = relu, bit1 = bf16 output.
// ---------------------------------------------------------------------------
__global__ __launch_bounds__(256) void gemm_bf16_wide(
    const float* __restrict__ A, const float* __restrict__ A2,
    const unsigned short* __restrict__ BT, const float* __restrict__ bias,
    void* __restrict__ Cout, int M, int N, int K, int flags)
{
    __shared__ uint4 As4[64 * 4];    // 4 KB
    __shared__ uint4 Bs4[256 * 4];   // 16 KB

    const int tid = threadIdx.x;
    const int lane = tid & 63;
    const int wave = tid >> 6;       // column quadrant 0..3
    const int row0 = blockIdx.x * 64;
    const int col0 = blockIdx.y * 256;

    f32x4 acc[4][4];
    #pragma unroll
    for (int i = 0; i < 4; ++i)
        #pragma unroll
        for (int j = 0; j < 4; ++j)
            acc[i][j] = {0.f, 0.f, 0.f, 0.f};

    const int ar = tid >> 2;         // A row 0..63
    const int ac = tid & 3;          // A chunk
    const int agr = row0 + ar;
    const bool aok = agr < M;
    const int lr = lane & 15;
    const int lc = lane >> 4;

    const bf16x8* Asb = (const bf16x8*)As4;
    const bf16x8* Bsb = (const bf16x8*)Bs4;

    for (int k0 = 0; k0 < K; k0 += 32) {
        // ---- global loads ----
        float fl[8];
        #pragma unroll
        for (int j = 0; j < 8; ++j) fl[j] = 0.f;
        if (aok) {
            const float* ap = A + (size_t)agr * K + k0 + ac * 8;
            float4 t0 = *(const float4*)ap;
            float4 t1 = *(const float4*)(ap + 4);
            fl[0] = t0.x; fl[1] = t0.y; fl[2] = t0.z; fl[3] = t0.w;
            fl[4] = t1.x; fl[5] = t1.y; fl[6] = t1.z; fl[7] = t1.w;
            if (A2) {
                const float* ap2 = A2 + (size_t)agr * K + k0 + ac * 8;
                float4 s0 = *(const float4*)ap2;
                float4 s1 = *(const float4*)(ap2 + 4);
                fl[0] += s0.x; fl[1] += s0.y; fl[2] += s0.z; fl[3] += s0.w;
                fl[4] += s1.x; fl[5] += s1.y; fl[6] += s1.z; fl[7] += s1.w;
            }
        }
        uint4 bq[4];
        #pragma unroll
        for (int i = 0; i < 4; ++i) {
            int r = i * 64 + (tid >> 2);
            int bgr = col0 + r;
            if (bgr >= N) bgr = N - 1;
            bq[i] = *(const uint4*)(BT + (size_t)bgr * K + k0 + (tid & 3) * 8);
        }

        __syncthreads();   // previous iteration's fragment reads done
        {
            union { unsigned short us[8]; uint4 q; } pk;
            #pragma unroll
            for (int j = 0; j < 8; ++j) pk.us[j] = f2bf(fl[j]);
            As4[ar * 4 + (ac ^ SW(ar))] = pk.q;
        }
        #pragma unroll
        for (int i = 0; i < 4; ++i) {
            int r = i * 64 + (tid >> 2);
            Bs4[r * 4 + ((tid & 3) ^ SW(r))] = bq[i];
        }
        __syncthreads();

        // ---- fragments + MFMA ----
        bf16x8 af[4], bfr[4];
        #pragma unroll
        for (int mi = 0; mi < 4; ++mi) {
            int r = mi * 16 + lr;
            af[mi] = Asb[r * 4 + (lc ^ SW(r))];
        }
        #pragma unroll
        for (int ni = 0; ni < 4; ++ni) {
            int r = wave * 64 + ni * 16 + lr;
            bfr[ni] = Bsb[r * 4 + (lc ^ SW(r))];
        }
        #pragma unroll
        for (int mi = 0; mi < 4; ++mi)
            #pragma unroll
            for (int ni = 0; ni < 4; ++ni)
                acc[mi][ni] = __builtin_amdgcn_mfma_f32_16x16x32_bf16(
                    af[mi], bfr[ni], acc[mi][ni], 0, 0, 0);
    }

    // ---- epilogue: col=lane&15 (+tile), row=(lane>>4)*4+reg ----
    const int relu = flags & 1;
    const int obf = flags & 2;
    #pragma unroll
    for (int ni = 0; ni < 4; ++ni) {
        int col = col0 + wave * 64 + ni * 16 + lr;
        if (col >= N) continue;
        float bval = bias[col];
        #pragma unroll
        for (int mi = 0; mi < 4; ++mi) {
            #pragma unroll
            for (int rg = 0; rg < 4; ++rg) {
                int row = row0 + mi * 16 + lc * 4 + rg;
                if (row < M) {
                    float o = acc[mi][ni][rg] + bval;
                    if (relu) o = fmaxf(o, 0.f);
                    if (obf) ((unsigned short*)Cout)[(size_t)row * N + col] = f2bf(o);
                    else     ((float*)Cout)[(size_t)row * N + col] = o;
                }
            }
        }
    }
}

// ---------------------------------------------------------------------------
// MFMA flash self-attention (unchanged from round 5)
// ---------------------------------------------------------------------------
__global__ __launch_bounds__(256) void attn_mfma_kernel(
    const float* __restrict__ q, const float* __restrict__ k,
    const float* __restrict__ v, float* __restrict__ out)
{
    __shared__ uint4 Kls[64 * 4];
    __shared__ uint4 Vtls[32 * 8];

    const int tid = threadIdx.x;
    const int lane = tid & 63;
    const int wave = tid >> 6;
    const int qcol = lane & 15;
    const int g = lane >> 4;
    const int bh = blockIdx.x;
    const int h = bh & 7, b = bh >> 3;
    const int qg = blockIdx.y * 64 + wave * 16 + qcol;
    const int qc = qg < NQ ? qg : NQ - 1;

    bf16x8 qf;
    {
        const float sc = 0.17677669529663687f;
        const float* qp = q + ((size_t)(b * NQ + qc)) * DM + h * 32 + g * 8;
        float4 f0 = *(const float4*)qp;
        float4 f1 = *(const float4*)(qp + 4);
        union { unsigned short us[8]; bf16x8 v8; } pk;
        pk.us[0] = f2bf(f0.x * sc); pk.us[1] = f2bf(f0.y * sc);
        pk.us[2] = f2bf(f0.z * sc); pk.us[3] = f2bf(f0.w * sc);
        pk.us[4] = f2bf(f1.x * sc); pk.us[5] = f2bf(f1.y * sc);
        pk.us[6] = f2bf(f1.z * sc); pk.us[7] = f2bf(f1.w * sc);
        qf = pk.v8;
    }

    float mrun = -3.0e38f, lrun = 0.f;
    f32x4 oacc[2];
    oacc[0] = {0.f, 0.f, 0.f, 0.f};
    oacc[1] = {0.f, 0.f, 0.f, 0.f};
    const f32x4 zacc = {0.f, 0.f, 0.f, 0.f};

    const int kidx = tid >> 2, kdc = tid & 3;
    const int vkp = tid >> 3, vdc = tid & 7;
    const bf16x8* Kb = (const bf16x8*)Kls;
    const bf16x8* Vb = (const bf16x8*)Vtls;
    unsigned int* V32 = (unsigned int*)Vtls;

    for (int jb = 0; jb < NQ; jb += 64) {
        __syncthreads();
        {
            int gk = jb + kidx;
            float4 f0 = make_float4(0.f, 0.f, 0.f, 0.f), f1 = f0;
            if (gk < NQ) {
                const float* kp = k + ((size_t)(b * NQ + gk)) * DM + h * 32 + kdc * 8;
                f0 = *(const float4*)kp;
                f1 = *(const float4*)(kp + 4);
            }
            union { unsigned short us[8]; uint4 u; } pk;
            pk.us[0] = f2bf(f0.x); pk.us[1] = f2bf(f0.y);
            pk.us[2] = f2bf(f0.z); pk.us[3] = f2bf(f0.w);
            pk.us[4] = f2bf(f1.x); pk.us[5] = f2bf(f1.y);
            pk.us[6] = f2bf(f1.z); pk.us[7] = f2bf(f1.w);
            Kls[kidx * 4 + (kdc ^ ((kidx >> 1) & 3))] = pk.u;
        }
        {
            int k0g = jb + 2 * vkp;
            float4 v0 = make_float4(0.f, 0.f, 0.f, 0.f), v1 = v0;
            if (k0g < NQ)
                v0 = *(const float4*)(v + ((size_t)(b * NQ + k0g)) * DM + h * 32 + vdc * 4);
            if (k0g + 1 < NQ)
                v1 = *(const float4*)(v + ((size_t)(b * NQ + k0g + 1)) * DM + h * 32 + vdc * 4);
            float a0[4] = {v0.x, v0.y, v0.z, v0.w};
            float a1[4] = {v1.x, v1.y, v1.z, v1.w};
            #pragma unroll
            for (int j = 0; j < 4; ++j) {
                int d = vdc * 4 + j;
                unsigned int val = (unsigned int)f2bf(a0[j]) | ((unsigned int)f2bf(a1[j]) << 16);
                V32[d * 32 + ((vkp >> 2) ^ (d & 7)) * 4 + (vkp & 3)] = val;
            }
        }
        __syncthreads();

        f32x4 sacc[4];
        #pragma unroll
        for (int kt = 0; kt < 4; ++kt) {
            int key = kt * 16 + qcol;
            bf16x8 kf = Kb[key * 4 + (g ^ ((key >> 1) & 3))];
            sacc[kt] = __builtin_amdgcn_mfma_f32_16x16x32_bf16(kf, qf, zacc, 0, 0, 0);
        }
        if (jb + 64 > NQ) {
            #pragma unroll
            for (int kt = 0; kt < 4; ++kt)
                #pragma unroll
                for (int r = 0; r < 4; ++r)
                    if (jb + kt * 16 + 4 * g + r >= NQ) sacc[kt][r] = -3.0e38f;
        }

        float mloc = -3.0e38f;
        #pragma unroll
        for (int kt = 0; kt < 4; ++kt)
            #pragma unroll
            for (int r = 0; r < 4; ++r)
                mloc = fmaxf(mloc, sacc[kt][r]);
        mloc = fmaxf(mloc, __shfl_xor(mloc, 16));
        mloc = fmaxf(mloc, __shfl_xor(mloc, 32));
        float mnew = fmaxf(mrun, mloc);
        float corr = __expf(mrun - mnew);
        mrun = mnew;

        float lloc = 0.f;
        unsigned int pk2[4][2];
        #pragma unroll
        for (int kt = 0; kt < 4; ++kt) {
            float p0 = __expf(sacc[kt][0] - mnew);
            float p1 = __expf(sacc[kt][1] - mnew);
            float p2 = __expf(sacc[kt][2] - mnew);
            float p3 = __expf(sacc[kt][3] - mnew);
            lloc += p0 + p1 + p2 + p3;
            pk2[kt][0] = (unsigned int)f2bf(p0) | ((unsigned int)f2bf(p1) << 16);
            pk2[kt][1] = (unsigned int)f2bf(p2) | ((unsigned int)f2bf(p3) << 16);
        }
        lloc += __shfl_xor(lloc, 16);
        lloc += __shfl_xor(lloc, 32);
        lrun = lrun * corr + lloc;
        #pragma unroll
        for (int ni = 0; ni < 2; ++ni)
            #pragma unroll
            for (int r = 0; r < 4; ++r)
                oacc[ni][r] *= corr;

        const int s0 = qcol + 32 * (g & 1);
        const bool hi = (g >> 1) != 0;
        #pragma unroll
        for (int tp = 0; tp < 2; ++tp) {
            int A0 = (int)pk2[2 * tp][0], A1 = (int)pk2[2 * tp][1];
            int B0 = (int)pk2[2 * tp + 1][0], B1 = (int)pk2[2 * tp + 1][1];
            int a0 = __shfl(A0, s0),      a1 = __shfl(A1, s0);
            int b0 = __shfl(B0, s0),      b1 = __shfl(B1, s0);
            int a2 = __shfl(A0, s0 + 16), a3 = __shfl(A1, s0 + 16);
            int b2 = __shfl(B0, s0 + 16), b3 = __shfl(B1, s0 + 16);
            union { unsigned int u[4]; bf16x8 v8; } pf;
            pf.u[0] = hi ? (unsigned int)b0 : (unsigned int)a0;
            pf.u[1] = hi ? (unsigned int)b1 : (unsigned int)a1;
            pf.u[2] = hi ? (unsigned int)b2 : (unsigned int)a2;
            pf.u[3] = hi ? (unsigned int)b3 : (unsigned int)a3;
            #pragma unroll
            for (int ni = 0; ni < 2; ++ni) {
                int d = ni * 16 + qcol;
                bf16x8 vf = Vb[d * 8 + ((4 * tp + g) ^ (d & 7))];
                oacc[ni] = __builtin_amdgcn_mfma_f32_16x16x32_bf16(vf, pf.v8, oacc[ni], 0, 0, 0);
            }
        }
    }

    if (qg < NQ) {
        float inv = 1.f / lrun;
        float* op = out + ((size_t)(b * NQ + qg)) * DM + h * 32;
        float4 o0, o1;
        o0.x = oacc[0][0] * inv; o0.y = oacc[0][1] * inv;
        o0.z = oacc[0][2] * inv; o0.w = oacc[0][3] * inv;
        o1.x = oacc[1][0] * inv; o1.y = oacc[1][1] * inv;
        o1.z = oacc[1][2] * inv; o1.w = oacc[1][3] * inv;
        *(float4*)(op + 4 * g) = o0;
        *(float4*)(op + 16 + 4 * g) = o1;
    }
}

// ---------------------------------------------------------------------------
__global__ __launch_bounds__(256) void aw_softmax_kernel(float* __restrict__ aw)
{
    int t = blockIdx.x * 256 + threadIdx.x;
    if (t >= BS * NQ * 8) return;
    float* p = aw + (size_t)t * 16;
    float vals[16];
    #pragma unroll
    for (int i = 0; i < 4; ++i) {
        float4 f = *(const float4*)(p + i * 4);
        vals[4 * i + 0] = f.x; vals[4 * i + 1] = f.y;
        vals[4 * i + 2] = f.z; vals[4 * i + 3] = f.w;
    }
    float mx = vals[0];
    #pragma unroll
    for (int i = 1; i < 16; ++i) mx = fmaxf(mx, vals[i]);
    float sum = 0.f;
    #pragma unroll
    for (int i = 0; i < 16; ++i) { vals[i] = __expf(vals[i] - mx); sum += vals[i]; }
    float inv = 1.f / sum;
    #pragma unroll
    for (int i = 0; i < 4; ++i) {
        float4 f;
        f.x = vals[4 * i + 0] * inv; f.y = vals[4 * i + 1] * inv;
        f.z = vals[4 * i + 2] * inv; f.w = vals[4 * i + 3] * inv;
        *(float4*)(p + i * 4) = f;
    }
}

// ---------------------------------------------------------------------------
// Deformable sampling over bf16 value table. lane = h*8 + c.
// ---------------------------------------------------------------------------
__global__ __launch_bounds__(256) void deform_kernel(
    const unsigned short* __restrict__ value, const float* __restrict__ off,
    const float* __restrict__ aw, const float* __restrict__ rbbox,
    float* __restrict__ dout)
{
    int t = blockIdx.x * 256 + threadIdx.x;
    if (t >= BS * NQ * 64) return;
    int c = t & 7;
    int h = (t >> 3) & 7;
    int bq = t >> 6;
    int b = bq / NQ;

    const int Hs[4]     = {100, 50, 25, 13};
    const int Wsz[4]    = {100, 50, 25, 13};
    const int Starts[4] = {0, 10000, 12500, 13125};

    float4 rb = *(const float4*)(rbbox + (size_t)bq * 4);
    const float* offp = off + (size_t)bq * 256 + h * 32;
    const float* awp  = aw + (size_t)bq * 128 + h * 16;
    const unsigned short* vb = value + ((size_t)b * LEN_V) * 256 + h * 32 + c * 4;

    float4 acc = make_float4(0.f, 0.f, 0.f, 0.f);
    #pragma unroll
    for (int l = 0; l < 4; ++l) {
        const int H = Hs[l], W = Wsz[l], st = Starts[l];
        #pragma unroll
        for (int p = 0; p < 4; ++p) {
            float ox = offp[l * 8 + p * 2 + 0];
            float oy = offp[l * 8 + p * 2 + 1];
            float a_w = awp[l * 4 + p];
            float xx = (rb.x + ox * 0.125f * rb.z) * W - 0.5f;
            float yy = (rb.y + oy * 0.125f * rb.w) * H - 0.5f;
            float x0f = floorf(xx), y0f = floorf(yy);
            float fx = xx - x0f, fy = yy - y0f;
            int x0 = (int)x0f, y0 = (int)y0f;
            #pragma unroll
            for (int dy = 0; dy < 2; ++dy) {
                int yi = y0 + dy;
                float wy = dy ? fy : (1.f - fy);
                bool vy = (yi >= 0) && (yi < H);
                int yc = min(max(yi, 0), H - 1);
                #pragma unroll
                for (int dx = 0; dx < 2; ++dx) {
                    int xi = x0 + dx;
                    float wx = dx ? fx : (1.f - fx);
                    bool vx = (xi >= 0) && (xi < W);
                    int xc = min(max(xi, 0), W - 1);
                    float wgt = a_w * wy * wx * ((vx && vy) ? 1.f : 0.f);
                    ushort4 gv = *(const ushort4*)(vb + (size_t)(st + yc * W + xc) * 256);
                    acc.x += wgt * bf2f(gv.x); acc.y += wgt * bf2f(gv.y);
                    acc.z += wgt * bf2f(gv.z); acc.w += wgt * bf2f(gv.w);
                }
            }
        }
    }
    *(float4*)(dout + (size_t)bq * 256 + h * 32 + c * 4) = acc;
}

// ---------------------------------------------------------------------------
__global__ __launch_bounds__(256) void ln_kernel(
    const float* __restrict__ x, const float* __restrict__ dx,
    const float* __restrict__ g, const float* __restrict__ bt,
    float* __restrict__ out, int rows)
{
    int row = blockIdx.x * 4 + (threadIdx.x >> 6);
    if (row >= rows) return;
    int lane = threadIdx.x & 63;
    size_t base = (size_t)row * 256 + lane * 4;
    float4 xv = *(const float4*)(x + base);
    float4 dv = *(const float4*)(dx + base);
    float a0 = xv.x + dv.x, a1 = xv.y + dv.y, a2 = xv.z + dv.z, a3 = xv.w + dv.w;
    float s = a0 + a1 + a2 + a3;
    float s2 = a0 * a0 + a1 * a1 + a2 * a2 + a3 * a3;
    #pragma unroll
    for (int o = 32; o; o >>= 1) {
        s += __shfl_xor(s, o);
        s2 += __shfl_xor(s2, o);
    }
    float mean = s * (1.f / 256.f);
    float var = s2 * (1.f / 256.f) - mean * mean;
    float inv = rsqrtf(var + 1e-5f);
    float4 gv = *(const float4*)(g + lane * 4);
    float4 bv = *(const float4*)(bt + lane * 4);
    float4 r;
    r.x = (a0 - mean) * inv * gv.x + bv.x;
    r.y = (a1 - mean) * inv * gv.y + bv.y;
    r.z = (a2 - mean) * inv * gv.z + bv.z;
    r.w = (a3 - mean) * inv * gv.w + bv.w;
    *(float4*)(out + base) = r;
}

// ---------------------------------------------------------------------------
extern "C" void kernel_launch(void* const* d_in, const int* in_sizes, int n_in,
                              void* d_out, int out_size, void* d_ws, size_t ws_size,
                              hipStream_t stream)
{
    const float* embed = (const float*)d_in[0];
    const float* rbbox = (const float*)d_in[1];
    const float* feats = (const float*)d_in[2];
    const float* qpos  = (const float*)d_in[3];
    const float* Wq = (const float*)d_in[4];  const float* bq = (const float*)d_in[5];
    const float* Wk = (const float*)d_in[6];  const float* bk = (const float*)d_in[7];
    const float* Wv = (const float*)d_in[8];  const float* bv = (const float*)d_in[9];
    const float* Wo = (const float*)d_in[10]; const float* bo = (const float*)d_in[11];
    const float* g1 = (const float*)d_in[12]; const float* b1 = (const float*)d_in[13];
    const float* Wval = (const float*)d_in[14]; const float* bval = (const float*)d_in[15];
    const float* Woff = (const float*)d_in[16]; const float* boff = (const float*)d_in[17];
    const float* Waw  = (const float*)d_in[18]; const float* baw  = (const float*)d_in[19];
    const float* Wop  = (const float*)d_in[20]; const float* bop  = (const float*)d_in[21];
    const float* g2 = (const float*)d_in[22]; const float* b2 = (const float*)d_in[23];
    const float* W1 = (const float*)d_in[24]; const float* bf1 = (const float*)d_in[25];
    const float* W2 = (const float*)d_in[26]; const float* bf2 = (const float*)d_in[27];
    const float* g3 = (const float*)d_in[28]; const float* b3 = (const float*)d_in[29];

    const int M = BS * NQ;                 // 7200
    const int MV = BS * LEN_V;             // 106352
    const size_t E = (size_t)M * DM;       // 1,843,200 floats
    const size_t VAL = (size_t)MV * DM;    // region sized as floats (only half used now)

    float* ws = (float*)d_ws;
    float* valueb = ws;                    // bf16 value table lives here (54.5 MB)
    float* qb   = ws + VAL;                // E
    float* kb   = qb + E;                  // E
    float* vbuf = kb + E;                  // E
    float* attb = vbuf + E;                // E
    float* e1b  = attb + E;                // E
    unsigned short* wbase = (unsigned short*)(e1b + E);
    unsigned short* wq_t   = wbase;
    unsigned short* wk_t   = wbase + 65536;
    unsigned short* wv_t   = wbase + 131072;
    unsigned short* wo_t   = wbase + 196608;
    unsigned short* wval_t = wbase + 262144;
    unsigned short* woff_t = wbase + 327680;
    unsigned short* waw_t  = wbase + 393216;
    unsigned short* wop_t  = wbase + 425984;
    unsigned short* w1_t   = wbase + 491520;
    unsigned short* w2_t   = wbase + 753664;

    unsigned short* valuebf = (unsigned short*)valueb;  // bf16 value table
    float* sab   = qb;      // Wo output
    float* offb  = kb;      // sampling offsets
    float* awbuf = vbuf;    // attention weights (N=128)
    float* doutb = attb;    // deformable output
    float* cab   = qb;      // Wop output
    float* e2b   = kb;      // embed after LN2
    float* ffhb  = valueb;  // FFN hidden fp32 (29.5MB), after deform consumed value
    float* ffb   = vbuf;    // FFN output

    dim3 blk(256);
    auto gg = [](int m, int n) { return dim3((m + 63) / 64, (n + 255) / 256); };

    // 0: weight prep
    {
        WPrepArgs a;
        a.w[0] = {Wq,   wq_t,   256, 256};
        a.w[1] = {Wk,   wk_t,   256, 256};
        a.w[2] = {Wv,   wv_t,   256, 256};
        a.w[3] = {Wo,   wo_t,   256, 256};
        a.w[4] = {Wval, wval_t, 256, 256};
        a.w[5] = {Woff, woff_t, 256, 256};
        a.w[6] = {Waw,  waw_t,  256, 128};
        a.w[7] = {Wop,  wop_t,  256, 256};
        a.w[8] = {W1,   w1_t,   256, 1024};
        a.w[9] = {W2,   w2_t,   1024, 256};
        wprep_kernel<<<dim3(32, 32, 10), blk, 0, stream>>>(a);
    }

    // 1-3: q, k, v projections
    gemm_bf16_wide<<<gg(M, 256), blk, 0, stream>>>(embed, qpos, wq_t, bq, qb, M, 256, 256, 0);
    gemm_bf16_wide<<<gg(M, 256), blk, 0, stream>>>(embed, qpos, wk_t, bk, kb, M, 256, 256, 0);
    gemm_bf16_wide<<<gg(M, 256), blk, 0, stream>>>(embed, nullptr, wv_t, bv, vbuf, M, 256, 256, 0);
    // 4: self-attention (MFMA flash)
    attn_mfma_kernel<<<dim3(BS * 8, (NQ + 63) / 64), blk, 0, stream>>>(qb, kb, vbuf, attb);
    // 5: output projection
    gemm_bf16_wide<<<gg(M, 256), blk, 0, stream>>>(attb, nullptr, wo_t, bo, sab, M, 256, 256, 0);
    // 6: LN1
    ln_kernel<<<dim3((M + 3) / 4), blk, 0, stream>>>(embed, sab, g1, b1, e1b, M);
    // 7: value projection (big GEMM) -> bf16 output
    gemm_bf16_wide<<<gg(MV, 256), blk, 0, stream>>>(feats, nullptr, wval_t, bval, valuebf, MV, 256, 256, 2);
    // 8-9: offsets + attention-weight logits (query = e1 + qpos fused)
    gemm_bf16_wide<<<gg(M, 256), blk, 0, stream>>>(e1b, qpos, woff_t, boff, offb, M, 256, 256, 0);
    gemm_bf16_wide<<<gg(M, 128), blk, 0, stream>>>(e1b, qpos, waw_t, baw, awbuf, M, 128, 256, 0);
    // 10: softmax over 16
    aw_softmax_kernel<<<dim3((BS * NQ * 8 + 255) / 256), blk, 0, stream>>>(awbuf);
    // 11: deformable sampling (bf16 gathers)
    deform_kernel<<<dim3((BS * NQ * 64 + 255) / 256), blk, 0, stream>>>(valuebf, offb, awbuf, rbbox, doutb);
    // 12: output projection of deformable attention
    gemm_bf16_wide<<<gg(M, 256), blk, 0, stream>>>(doutb, nullptr, wop_t, bop, cab, M, 256, 256, 0);
    // 13: LN2
    ln_kernel<<<dim3((M + 3) / 4), blk, 0, stream>>>(e1b, cab, g2, b2, e2b, M);
    // 14-15: FFN (relu fused in FFN1)
    gemm_bf16_wide<<<gg(M, 1024), blk, 0, stream>>>(e2b, nullptr, w1_t, bf1, ffhb, M, 1024, 256, 1);
    gemm_bf16_wide<<<gg(M, 256), blk, 0, stream>>>(ffhb, nullptr, w2_t, bf2, ffb, M, 256, 1024, 0);
    // 16: LN3 -> out
    ln_kernel<<<dim3((M + 3) / 4), blk, 0, stream>>>(e2b, ffb, g3, b3, (float*)d_out, M);
}

// Round 7
// 332.032 us; speedup vs baseline: 1.4592x; 1.4592x over previous
//
#include <hip/hip_runtime.h>
#include <hip/hip_bf16.h>
#include <cstddef>

#define BS 8
#define NQ 900
#define DM 256
#define LEN_V 13294

using bf16x8 = __attribute__((ext_vector_type(8))) __bf16;
using f32x4  = __attribute__((ext_vector_type(4))) float;

__device__ __forceinline__ unsigned short f2bf(float f) {
    union { float f; unsigned int u; } v; v.f = f;
    unsigned int r = v.u + 0x7FFFu + ((v.u >> 16) & 1u);
    return (unsigned short)(r >> 16);
}
__device__ __forceinline__ float bf2f(unsigned short u) {
    union { unsigned int u; float f; } v; v.u = ((unsigned int)u) << 16;
    return v.f;
}

#define SW(r) (((r) + ((r) >> 2)) & 3)

#define FLAG_RELU 1
#define FLAG_OBF  2
#define FLAG_SWAP 4

// ---------------------------------------------------------------------------
// Batched weight prep: fp32 W[K][N] -> bf16 WT[N][K]
// ---------------------------------------------------------------------------
struct WDesc { const float* src; unsigned short* dst; int K; int N; };
struct WPrepArgs { WDesc w[10]; };

__global__ __launch_bounds__(256) void wprep_kernel(WPrepArgs args)
{
    WDesc d = args.w[blockIdx.z];
    int k0 = blockIdx.x * 32;
    int n0 = blockIdx.y * 32;
    if (k0 >= d.K || n0 >= d.N) return;
    __shared__ unsigned short t[32][33];
    int tx = threadIdx.x & 31, ty = threadIdx.x >> 5;
    #pragma unroll
    for (int i = 0; i < 4; ++i) {
        int kk = ty + i * 8;
        t[kk][tx] = f2bf(d.src[(size_t)(k0 + kk) * d.N + n0 + tx]);
    }
    __syncthreads();
    #pragma unroll
    for (int i = 0; i < 4; ++i) {
        int nn = ty + i * 8;
        d.dst[(size_t)(n0 + nn) * d.K + k0 + tx] = t[tx][nn];
    }
}

// ---------------------------------------------------------------------------
// bf16 MFMA GEMM (round-5 shape): C[M,N] = bf16(A [+A2]) @ B + bias.
// BM=128, BN=64, BK=32; 256 threads = 4 waves (2x2), wave 64x32, 4x2 frags.
// flags: FLAG_RELU | FLAG_OBF (bf16 out via LDS repack) | FLAG_SWAP
// (blockIdx.x=cols, blockIdx.y=rows for A-panel L3 reuse).
// ---------------------------------------------------------------------------
__global__ __launch_bounds__(256) void gemm_bf16_kernel(
    const float* __restrict__ A, const float* __restrict__ A2,
    const unsigned short* __restrict__ BT, const float* __restrict__ bias,
    void* __restrict__ Cout, int M, int N, int K, int flags)
{
    __shared__ uint4 SMEM[768];            // 12 KB: A stage 8KB + B stage 4KB
    uint4* As4 = SMEM;                     // [128*4]
    uint4* Bs4 = SMEM + 512;               // [64*4]

    const int tid = threadIdx.x;
    const int lane = tid & 63;
    const int wave = tid >> 6;
    const int wm = wave >> 1;
    const int wn = wave & 1;
    const int row0 = (flags & FLAG_SWAP ? blockIdx.y : blockIdx.x) * 128;
    const int col0 = (flags & FLAG_SWAP ? blockIdx.x : blockIdx.y) * 64;

    f32x4 acc[4][2];
    #pragma unroll
    for (int i = 0; i < 4; ++i)
        #pragma unroll
        for (int j = 0; j < 2; ++j)
            acc[i][j] = {0.f, 0.f, 0.f, 0.f};

    const int ar  = tid >> 1;
    const int ah  = (tid & 1) * 16;
    const int acb = (tid & 1) * 2;
    const int agr = row0 + ar;
    const bool aok = agr < M;
    const int br  = tid >> 2;
    const int bseg = tid & 3;
    const int bgr = col0 + br;

    const int lr = lane & 15;
    const int lc = lane >> 4;

    const bf16x8* Asb = (const bf16x8*)As4;
    const bf16x8* Bsb = (const bf16x8*)Bs4;

    for (int k0 = 0; k0 < K; k0 += 32) {
        float fl[16];
        #pragma unroll
        for (int j = 0; j < 16; ++j) fl[j] = 0.f;
        if (aok) {
            const float* ap = A + (size_t)agr * K + k0 + ah;
            #pragma unroll
            for (int j = 0; j < 4; ++j) {
                float4 t = *(const float4*)(ap + j * 4);
                fl[j*4+0] = t.x; fl[j*4+1] = t.y; fl[j*4+2] = t.z; fl[j*4+3] = t.w;
            }
            if (A2) {
                const float* ap2 = A2 + (size_t)agr * K + k0 + ah;
                #pragma unroll
                for (int j = 0; j < 4; ++j) {
                    float4 t = *(const float4*)(ap2 + j * 4);
                    fl[j*4+0] += t.x; fl[j*4+1] += t.y; fl[j*4+2] += t.z; fl[j*4+3] += t.w;
                }
            }
        }
        uint4 bvq = *(const uint4*)(BT + (size_t)bgr * K + k0 + bseg * 8);

        __syncthreads();
        union { unsigned short us[8]; uint4 q; } pk0, pk1;
        #pragma unroll
        for (int j = 0; j < 8; ++j) { pk0.us[j] = f2bf(fl[j]); pk1.us[j] = f2bf(fl[8 + j]); }
        As4[ar * 4 + ((acb + 0) ^ SW(ar))] = pk0.q;
        As4[ar * 4 + ((acb + 1) ^ SW(ar))] = pk1.q;
        Bs4[br * 4 + (bseg ^ SW(br))] = bvq;
        __syncthreads();

        bf16x8 af[4], bfr[2];
        #pragma unroll
        for (int mi = 0; mi < 4; ++mi) {
            int r = wm * 64 + mi * 16 + lr;
            af[mi] = Asb[r * 4 + (lc ^ SW(r))];
        }
        #pragma unroll
        for (int ni = 0; ni < 2; ++ni) {
            int r = wn * 32 + ni * 16 + lr;
            bfr[ni] = Bsb[r * 4 + (lc ^ SW(r))];
        }
        #pragma unroll
        for (int mi = 0; mi < 4; ++mi)
            #pragma unroll
            for (int ni = 0; ni < 2; ++ni)
                acc[mi][ni] = __builtin_amdgcn_mfma_f32_16x16x32_bf16(
                    af[mi], bfr[ni], acc[mi][ni], 0, 0, 0);
    }

    const int relu = flags & FLAG_RELU;
    if (!(flags & FLAG_OBF)) {
        // fp32 epilogue: col=lane&15 (+tiles), row=(lane>>4)*4+reg
        float* C = (float*)Cout;
        #pragma unroll
        for (int ni = 0; ni < 2; ++ni) {
            int col = col0 + wn * 32 + ni * 16 + lr;
            if (col >= N) continue;
            float bval = bias[col];
            #pragma unroll
            for (int mi = 0; mi < 4; ++mi) {
                #pragma unroll
                for (int rg = 0; rg < 4; ++rg) {
                    int row = row0 + wm * 64 + mi * 16 + lc * 4 + rg;
                    if (row < M) {
                        float o = acc[mi][ni][rg] + bval;
                        if (relu) o = fmaxf(o, 0.f);
                        C[(size_t)row * N + col] = o;
                    }
                }
            }
        }
    } else {
        // bf16 epilogue via LDS repack -> 16B/lane coalesced stores
        unsigned short* RP = (unsigned short*)SMEM;  // [64][72] shorts = 9216 B
        unsigned short* C = (unsigned short*)Cout;
        float bval[2];
        #pragma unroll
        for (int ni = 0; ni < 2; ++ni) {
            int col = col0 + wn * 32 + ni * 16 + lr;
            bval[ni] = (col < N) ? bias[col] : 0.f;
        }
        #pragma unroll
        for (int h2 = 0; h2 < 2; ++h2) {
            __syncthreads();
            if (wm == h2) {
                #pragma unroll
                for (int ni = 0; ni < 2; ++ni) {
                    int colL = wn * 32 + ni * 16 + lr;
                    #pragma unroll
                    for (int mi = 0; mi < 4; ++mi) {
                        #pragma unroll
                        for (int rg = 0; rg < 4; ++rg) {
                            int rowL = mi * 16 + lc * 4 + rg;
                            float o = acc[mi][ni][rg] + bval[ni];
                            if (relu) o = fmaxf(o, 0.f);
                            RP[rowL * 72 + colL] = f2bf(o);
                        }
                    }
                }
            }
            __syncthreads();
            #pragma unroll
            for (int it = 0; it < 2; ++it) {
                int r = it * 32 + (tid >> 3);
                int c = tid & 7;
                int grow = row0 + h2 * 64 + r;
                int gcol = col0 + c * 8;
                if (grow < M && gcol < N) {
                    uint4 vq = *(const uint4*)&RP[r * 72 + c * 8];
                    *(uint4*)(C + (size_t)grow * N + gcol) = vq;
                }
            }
        }
    }
}

// ---------------------------------------------------------------------------
// MFMA flash self-attention (unchanged from round 5)
// ---------------------------------------------------------------------------
__global__ __launch_bounds__(256) void attn_mfma_kernel(
    const float* __restrict__ q, const float* __restrict__ k,
    const float* __restrict__ v, float* __restrict__ out)
{
    __shared__ uint4 Kls[64 * 4];
    __shared__ uint4 Vtls[32 * 8];

    const int tid = threadIdx.x;
    const int lane = tid & 63;
    const int wave = tid >> 6;
    const int qcol = lane & 15;
    const int g = lane >> 4;
    const int bh = blockIdx.x;
    const int h = bh & 7, b = bh >> 3;
    const int qg = blockIdx.y * 64 + wave * 16 + qcol;
    const int qc = qg < NQ ? qg : NQ - 1;

    bf16x8 qf;
    {
        const float sc = 0.17677669529663687f;
        const float* qp = q + ((size_t)(b * NQ + qc)) * DM + h * 32 + g * 8;
        float4 f0 = *(const float4*)qp;
        float4 f1 = *(const float4*)(qp + 4);
        union { unsigned short us[8]; bf16x8 v8; } pk;
        pk.us[0] = f2bf(f0.x * sc); pk.us[1] = f2bf(f0.y * sc);
        pk.us[2] = f2bf(f0.z * sc); pk.us[3] = f2bf(f0.w * sc);
        pk.us[4] = f2bf(f1.x * sc); pk.us[5] = f2bf(f1.y * sc);
        pk.us[6] = f2bf(f1.z * sc); pk.us[7] = f2bf(f1.w * sc);
        qf = pk.v8;
    }

    float mrun = -3.0e38f, lrun = 0.f;
    f32x4 oacc[2];
    oacc[0] = {0.f, 0.f, 0.f, 0.f};
    oacc[1] = {0.f, 0.f, 0.f, 0.f};
    const f32x4 zacc = {0.f, 0.f, 0.f, 0.f};

    const int kidx = tid >> 2, kdc = tid & 3;
    const int vkp = tid >> 3, vdc = tid & 7;
    const bf16x8* Kb = (const bf16x8*)Kls;
    const bf16x8* Vb = (const bf16x8*)Vtls;
    unsigned int* V32 = (unsigned int*)Vtls;

    for (int jb = 0; jb < NQ; jb += 64) {
        __syncthreads();
        {
            int gk = jb + kidx;
            float4 f0 = make_float4(0.f, 0.f, 0.f, 0.f), f1 = f0;
            if (gk < NQ) {
                const float* kp = k + ((size_t)(b * NQ + gk)) * DM + h * 32 + kdc * 8;
                f0 = *(const float4*)kp;
                f1 = *(const float4*)(kp + 4);
            }
            union { unsigned short us[8]; uint4 u; } pk;
            pk.us[0] = f2bf(f0.x); pk.us[1] = f2bf(f0.y);
            pk.us[2] = f2bf(f0.z); pk.us[3] = f2bf(f0.w);
            pk.us[4] = f2bf(f1.x); pk.us[5] = f2bf(f1.y);
            pk.us[6] = f2bf(f1.z); pk.us[7] = f2bf(f1.w);
            Kls[kidx * 4 + (kdc ^ ((kidx >> 1) & 3))] = pk.u;
        }
        {
            int k0g = jb + 2 * vkp;
            float4 v0 = make_float4(0.f, 0.f, 0.f, 0.f), v1 = v0;
            if (k0g < NQ)
                v0 = *(const float4*)(v + ((size_t)(b * NQ + k0g)) * DM + h * 32 + vdc * 4);
            if (k0g + 1 < NQ)
                v1 = *(const float4*)(v + ((size_t)(b * NQ + k0g + 1)) * DM + h * 32 + vdc * 4);
            float a0[4] = {v0.x, v0.y, v0.z, v0.w};
            float a1[4] = {v1.x, v1.y, v1.z, v1.w};
            #pragma unroll
            for (int j = 0; j < 4; ++j) {
                int d = vdc * 4 + j;
                unsigned int val = (unsigned int)f2bf(a0[j]) | ((unsigned int)f2bf(a1[j]) << 16);
                V32[d * 32 + ((vkp >> 2) ^ (d & 7)) * 4 + (vkp & 3)] = val;
            }
        }
        __syncthreads();

        f32x4 sacc[4];
        #pragma unroll
        for (int kt = 0; kt < 4; ++kt) {
            int key = kt * 16 + qcol;
            bf16x8 kf = Kb[key * 4 + (g ^ ((key >> 1) & 3))];
            sacc[kt] = __builtin_amdgcn_mfma_f32_16x16x32_bf16(kf, qf, zacc, 0, 0, 0);
        }
        if (jb + 64 > NQ) {
            #pragma unroll
            for (int kt = 0; kt < 4; ++kt)
                #pragma unroll
                for (int r = 0; r < 4; ++r)
                    if (jb + kt * 16 + 4 * g + r >= NQ) sacc[kt][r] = -3.0e38f;
        }

        float mloc = -3.0e38f;
        #pragma unroll
        for (int kt = 0; kt < 4; ++kt)
            #pragma unroll
            for (int r = 0; r < 4; ++r)
                mloc = fmaxf(mloc, sacc[kt][r]);
        mloc = fmaxf(mloc, __shfl_xor(mloc, 16));
        mloc = fmaxf(mloc, __shfl_xor(mloc, 32));
        float mnew = fmaxf(mrun, mloc);
        float corr = __expf(mrun - mnew);
        mrun = mnew;

        float lloc = 0.f;
        unsigned int pk2[4][2];
        #pragma unroll
        for (int kt = 0; kt < 4; ++kt) {
            float p0 = __expf(sacc[kt][0] - mnew);
            float p1 = __expf(sacc[kt][1] - mnew);
            float p2 = __expf(sacc[kt][2] - mnew);
            float p3 = __expf(sacc[kt][3] - mnew);
            lloc += p0 + p1 + p2 + p3;
            pk2[kt][0] = (unsigned int)f2bf(p0) | ((unsigned int)f2bf(p1) << 16);
            pk2[kt][1] = (unsigned int)f2bf(p2) | ((unsigned int)f2bf(p3) << 16);
        }
        lloc += __shfl_xor(lloc, 16);
        lloc += __shfl_xor(lloc, 32);
        lrun = lrun * corr + lloc;
        #pragma unroll
        for (int ni = 0; ni < 2; ++ni)
            #pragma unroll
            for (int r = 0; r < 4; ++r)
                oacc[ni][r] *= corr;

        const int s0 = qcol + 32 * (g & 1);
        const bool hi = (g >> 1) != 0;
        #pragma unroll
        for (int tp = 0; tp < 2; ++tp) {
            int A0 = (int)pk2[2 * tp][0], A1 = (int)pk2[2 * tp][1];
            int B0 = (int)pk2[2 * tp + 1][0], B1 = (int)pk2[2 * tp + 1][1];
            int a0 = __shfl(A0, s0),      a1 = __shfl(A1, s0);
            int b0 = __shfl(B0, s0),      b1 = __shfl(B1, s0);
            int a2 = __shfl(A0, s0 + 16), a3 = __shfl(A1, s0 + 16);
            int b2 = __shfl(B0, s0 + 16), b3 = __shfl(B1, s0 + 16);
            union { unsigned int u[4]; bf16x8 v8; } pf;
            pf.u[0] = hi ? (unsigned int)b0 : (unsigned int)a0;
            pf.u[1] = hi ? (unsigned int)b1 : (unsigned int)a1;
            pf.u[2] = hi ? (unsigned int)b2 : (unsigned int)a2;
            pf.u[3] = hi ? (unsigned int)b3 : (unsigned int)a3;
            #pragma unroll
            for (int ni = 0; ni < 2; ++ni) {
                int d = ni * 16 + qcol;
                bf16x8 vf = Vb[d * 8 + ((4 * tp + g) ^ (d & 7))];
                oacc[ni] = __builtin_amdgcn_mfma_f32_16x16x32_bf16(vf, pf.v8, oacc[ni], 0, 0, 0);
            }
        }
    }

    if (qg < NQ) {
        float inv = 1.f / lrun;
        float* op = out + ((size_t)(b * NQ + qg)) * DM + h * 32;
        float4 o0, o1;
        o0.x = oacc[0][0] * inv; o0.y = oacc[0][1] * inv;
        o0.z = oacc[0][2] * inv; o0.w = oacc[0][3] * inv;
        o1.x = oacc[1][0] * inv; o1.y = oacc[1][1] * inv;
        o1.z = oacc[1][2] * inv; o1.w = oacc[1][3] * inv;
        *(float4*)(op + 4 * g) = o0;
        *(float4*)(op + 16 + 4 * g) = o1;
    }
}

// ---------------------------------------------------------------------------
__global__ __launch_bounds__(256) void aw_softmax_kernel(float* __restrict__ aw)
{
    int t = blockIdx.x * 256 + threadIdx.x;
    if (t >= BS * NQ * 8) return;
    float* p = aw + (size_t)t * 16;
    float vals[16];
    #pragma unroll
    for (int i = 0; i < 4; ++i) {
        float4 f = *(const float4*)(p + i * 4);
        vals[4 * i + 0] = f.x; vals[4 * i + 1] = f.y;
        vals[4 * i + 2] = f.z; vals[4 * i + 3] = f.w;
    }
    float mx = vals[0];
    #pragma unroll
    for (int i = 1; i < 16; ++i) mx = fmaxf(mx, vals[i]);
    float sum = 0.f;
    #pragma unroll
    for (int i = 0; i < 16; ++i) { vals[i] = __expf(vals[i] - mx); sum += vals[i]; }
    float inv = 1.f / sum;
    #pragma unroll
    for (int i = 0; i < 4; ++i) {
        float4 f;
        f.x = vals[4 * i + 0] * inv; f.y = vals[4 * i + 1] * inv;
        f.z = vals[4 * i + 2] * inv; f.w = vals[4 * i + 3] * inv;
        *(float4*)(p + i * 4) = f;
    }
}

// ---------------------------------------------------------------------------
// Deformable sampling over bf16 value table. lane = h*8 + c.
// ---------------------------------------------------------------------------
__global__ __launch_bounds__(256) void deform_kernel(
    const unsigned short* __restrict__ value, const float* __restrict__ off,
    const float* __restrict__ aw, const float* __restrict__ rbbox,
    float* __restrict__ dout)
{
    int t = blockIdx.x * 256 + threadIdx.x;
    if (t >= BS * NQ * 64) return;
    int c = t & 7;
    int h = (t >> 3) & 7;
    int bq = t >> 6;
    int b = bq / NQ;

    const int Hs[4]     = {100, 50, 25, 13};
    const int Wsz[4]    = {100, 50, 25, 13};
    const int Starts[4] = {0, 10000, 12500, 13125};

    float4 rb = *(const float4*)(rbbox + (size_t)bq * 4);
    const float* offp = off + (size_t)bq * 256 + h * 32;
    const float* awp  = aw + (size_t)bq * 128 + h * 16;
    const unsigned short* vb = value + ((size_t)b * LEN_V) * 256 + h * 32 + c * 4;

    float4 acc = make_float4(0.f, 0.f, 0.f, 0.f);
    #pragma unroll
    for (int l = 0; l < 4; ++l) {
        const int H = Hs[l], W = Wsz[l], st = Starts[l];
        #pragma unroll
        for (int p = 0; p < 4; ++p) {
            float ox = offp[l * 8 + p * 2 + 0];
            float oy = offp[l * 8 + p * 2 + 1];
            float a_w = awp[l * 4 + p];
            float xx = (rb.x + ox * 0.125f * rb.z) * W - 0.5f;
            float yy = (rb.y + oy * 0.125f * rb.w) * H - 0.5f;
            float x0f = floorf(xx), y0f = floorf(yy);
            float fx = xx - x0f, fy = yy - y0f;
            int x0 = (int)x0f, y0 = (int)y0f;
            #pragma unroll
            for (int dy = 0; dy < 2; ++dy) {
                int yi = y0 + dy;
                float wy = dy ? fy : (1.f - fy);
                bool vy = (yi >= 0) && (yi < H);
                int yc = min(max(yi, 0), H - 1);
                #pragma unroll
                for (int dx = 0; dx < 2; ++dx) {
                    int xi = x0 + dx;
                    float wx = dx ? fx : (1.f - fx);
                    bool vx = (xi >= 0) && (xi < W);
                    int xc = min(max(xi, 0), W - 1);
                    float wgt = a_w * wy * wx * ((vx && vy) ? 1.f : 0.f);
                    ushort4 gv = *(const ushort4*)(vb + (size_t)(st + yc * W + xc) * 256);
                    acc.x += wgt * bf2f(gv.x); acc.y += wgt * bf2f(gv.y);
                    acc.z += wgt * bf2f(gv.z); acc.w += wgt * bf2f(gv.w);
                }
            }
        }
    }
    *(float4*)(dout + (size_t)bq * 256 + h * 32 + c * 4) = acc;
}

// ---------------------------------------------------------------------------
__global__ __launch_bounds__(256) void ln_kernel(
    const float* __restrict__ x, const float* __restrict__ dx,
    const float* __restrict__ g, const float* __restrict__ bt,
    float* __restrict__ out, int rows)
{
    int row = blockIdx.x * 4 + (threadIdx.x >> 6);
    if (row >= rows) return;
    int lane = threadIdx.x & 63;
    size_t base = (size_t)row * 256 + lane * 4;
    float4 xv = *(const float4*)(x + base);
    float4 dv = *(const float4*)(dx + base);
    float a0 = xv.x + dv.x, a1 = xv.y + dv.y, a2 = xv.z + dv.z, a3 = xv.w + dv.w;
    float s = a0 + a1 + a2 + a3;
    float s2 = a0 * a0 + a1 * a1 + a2 * a2 + a3 * a3;
    #pragma unroll
    for (int o = 32; o; o >>= 1) {
        s += __shfl_xor(s, o);
        s2 += __shfl_xor(s2, o);
    }
    float mean = s * (1.f / 256.f);
    float var = s2 * (1.f / 256.f) - mean * mean;
    float inv = rsqrtf(var + 1e-5f);
    float4 gv = *(const float4*)(g + lane * 4);
    float4 bv = *(const float4*)(bt + lane * 4);
    float4 r;
    r.x = (a0 - mean) * inv * gv.x + bv.x;
    r.y = (a1 - mean) * inv * gv.y + bv.y;
    r.z = (a2 - mean) * inv * gv.z + bv.z;
    r.w = (a3 - mean) * inv * gv.w + bv.w;
    *(float4*)(out + base) = r;
}

// ---------------------------------------------------------------------------
extern "C" void kernel_launch(void* const* d_in, const int* in_sizes, int n_in,
                              void* d_out, int out_size, void* d_ws, size_t ws_size,
                              hipStream_t stream)
{
    const float* embed = (const float*)d_in[0];
    const float* rbbox = (const float*)d_in[1];
    const float* feats = (const float*)d_in[2];
    const float* qpos  = (const float*)d_in[3];
    const float* Wq = (const float*)d_in[4];  const float* bq = (const float*)d_in[5];
    const float* Wk = (const float*)d_in[6];  const float* bk = (const float*)d_in[7];
    const float* Wv = (const float*)d_in[8];  const float* bv = (const float*)d_in[9];
    const float* Wo = (const float*)d_in[10]; const float* bo = (const float*)d_in[11];
    const float* g1 = (const float*)d_in[12]; const float* b1 = (const float*)d_in[13];
    const float* Wval = (const float*)d_in[14]; const float* bval = (const float*)d_in[15];
    const float* Woff = (const float*)d_in[16]; const float* boff = (const float*)d_in[17];
    const float* Waw  = (const float*)d_in[18]; const float* baw  = (const float*)d_in[19];
    const float* Wop  = (const float*)d_in[20]; const float* bop  = (const float*)d_in[21];
    const float* g2 = (const float*)d_in[22]; const float* b2 = (const float*)d_in[23];
    const float* W1 = (const float*)d_in[24]; const float* bf1 = (const float*)d_in[25];
    const float* W2 = (const float*)d_in[26]; const float* bf2 = (const float*)d_in[27];
    const float* g3 = (const float*)d_in[28]; const float* b3 = (const float*)d_in[29];

    const int M = BS * NQ;                 // 7200
    const int MV = BS * LEN_V;             // 106352
    const size_t E = (size_t)M * DM;       // 1,843,200 floats
    const size_t VAL = (size_t)MV * DM;    // region sized as floats

    float* ws = (float*)d_ws;
    float* valueb = ws;                    // bf16 value table (54.5 MB of this region)
    float* qb   = ws + VAL;                // E
    float* kb   = qb + E;                  // E
    float* vbuf = kb + E;                  // E
    float* attb = vbuf + E;                // E
    float* e1b  = attb + E;                // E
    unsigned short* wbase = (unsigned short*)(e1b + E);
    unsigned short* wq_t   = wbase;
    unsigned short* wk_t   = wbase + 65536;
    unsigned short* wv_t   = wbase + 131072;
    unsigned short* wo_t   = wbase + 196608;
    unsigned short* wval_t = wbase + 262144;
    unsigned short* woff_t = wbase + 327680;
    unsigned short* waw_t  = wbase + 393216;
    unsigned short* wop_t  = wbase + 425984;
    unsigned short* w1_t   = wbase + 491520;
    unsigned short* w2_t   = wbase + 753664;

    unsigned short* valuebf = (unsigned short*)valueb;
    float* sab   = qb;      // Wo output
    float* offb  = kb;      // sampling offsets
    float* awbuf = vbuf;    // attention weights (N=128)
    float* doutb = attb;    // deformable output
    float* cab   = qb;      // Wop output
    float* e2b   = kb;      // embed after LN2
    float* ffhb  = valueb;  // FFN hidden fp32 (29.5 MB), after deform consumed value
    float* ffb   = vbuf;    // FFN output

    dim3 blk(256);
    // swapped grid: x = col-blocks (adjacent dispatches share the A panel)
    auto gs = [](int m, int n) { return dim3((n + 63) / 64, (m + 127) / 128); };

    // 0: weight prep
    {
        WPrepArgs a;
        a.w[0] = {Wq,   wq_t,   256, 256};
        a.w[1] = {Wk,   wk_t,   256, 256};
        a.w[2] = {Wv,   wv_t,   256, 256};
        a.w[3] = {Wo,   wo_t,   256, 256};
        a.w[4] = {Wval, wval_t, 256, 256};
        a.w[5] = {Woff, woff_t, 256, 256};
        a.w[6] = {Waw,  waw_t,  256, 128};
        a.w[7] = {Wop,  wop_t,  256, 256};
        a.w[8] = {W1,   w1_t,   256, 1024};
        a.w[9] = {W2,   w2_t,   1024, 256};
        wprep_kernel<<<dim3(32, 32, 10), blk, 0, stream>>>(a);
    }

    // 1-3: q, k, v projections
    gemm_bf16_kernel<<<gs(M, 256), blk, 0, stream>>>(embed, qpos, wq_t, bq, qb, M, 256, 256, FLAG_SWAP);
    gemm_bf16_kernel<<<gs(M, 256), blk, 0, stream>>>(embed, qpos, wk_t, bk, kb, M, 256, 256, FLAG_SWAP);
    gemm_bf16_kernel<<<gs(M, 256), blk, 0, stream>>>(embed, nullptr, wv_t, bv, vbuf, M, 256, 256, FLAG_SWAP);
    // 4: self-attention (MFMA flash)
    attn_mfma_kernel<<<dim3(BS * 8, (NQ + 63) / 64), blk, 0, stream>>>(qb, kb, vbuf, attb);
    // 5: output projection
    gemm_bf16_kernel<<<gs(M, 256), blk, 0, stream>>>(attb, nullptr, wo_t, bo, sab, M, 256, 256, FLAG_SWAP);
    // 6: LN1
    ln_kernel<<<dim3((M + 3) / 4), blk, 0, stream>>>(embed, sab, g1, b1, e1b, M);
    // 7: value projection (big GEMM) -> bf16 output via LDS repack
    gemm_bf16_kernel<<<gs(MV, 256), blk, 0, stream>>>(feats, nullptr, wval_t, bval, valuebf, MV, 256, 256, FLAG_SWAP | FLAG_OBF);
    // 8-9: offsets + attention-weight logits (query = e1 + qpos fused)
    gemm_bf16_kernel<<<gs(M, 256), blk, 0, stream>>>(e1b, qpos, woff_t, boff, offb, M, 256, 256, FLAG_SWAP);
    gemm_bf16_kernel<<<gs(M, 128), blk, 0, stream>>>(e1b, qpos, waw_t, baw, awbuf, M, 128, 256, FLAG_SWAP);
    // 10: softmax over 16
    aw_softmax_kernel<<<dim3((BS * NQ * 8 + 255) / 256), blk, 0, stream>>>(awbuf);
    // 11: deformable sampling (bf16 gathers)
    deform_kernel<<<dim3((BS * NQ * 64 + 255) / 256), blk, 0, stream>>>(valuebf, offb, awbuf, rbbox, doutb);
    // 12: output projection of deformable attention
    gemm_bf16_kernel<<<gs(M, 256), blk, 0, stream>>>(doutb, nullptr, wop_t, bop, cab, M, 256, 256, FLAG_SWAP);
    // 13: LN2
    ln_kernel<<<dim3((M + 3) / 4), blk, 0, stream>>>(e1b, cab, g2, b2, e2b, M);
    // 14-15: FFN (relu fused in FFN1)
    gemm_bf16_kernel<<<gs(M, 1024), blk, 0, stream>>>(e2b, nullptr, w1_t, bf1, ffhb, M, 1024, 256, FLAG_SWAP | FLAG_RELU);
    gemm_bf16_kernel<<<gs(M, 256), blk, 0, stream>>>(ffhb, nullptr, w2_t, bf2, ffb, M, 256, 1024, FLAG_SWAP);
    // 16: LN3 -> out
    ln_kernel<<<dim3((M + 3) / 4), blk, 0, stream>>>(e2b, ffb, g3, b3, (float*)d_out, M);
}

// Round 8
// 309.632 us; speedup vs baseline: 1.5647x; 1.0723x over previous
//
#include <hip/hip_runtime.h>
#include <hip/hip_bf16.h>
#include <cstddef>

#define BS 8
#define NQ 900
#define DM 256
#define LEN_V 13294

using bf16x8 = __attribute__((ext_vector_type(8))) __bf16;
using f32x4  = __attribute__((ext_vector_type(4))) float;

__device__ __forceinline__ unsigned short f2bf(float f) {
    union { float f; unsigned int u; } v; v.f = f;
    unsigned int r = v.u + 0x7FFFu + ((v.u >> 16) & 1u);
    return (unsigned short)(r >> 16);
}
__device__ __forceinline__ float bf2f(unsigned short u) {
    union { unsigned int u; float f; } v; v.u = ((unsigned int)u) << 16;
    return v.f;
}

#define SW(r) (((r) + ((r) >> 2)) & 3)

#define FLAG_RELU 1
#define FLAG_OBF  2
#define FLAG_SWAP 4
#define FLAG_QKV  8

// ---------------------------------------------------------------------------
// Batched weight prep: fp32 W[K][N] -> bf16 WT[N][K] (dst may be offset into
// a concatenated table)
// ---------------------------------------------------------------------------
struct WDesc { const float* src; unsigned short* dst; int K; int N; };
struct WPrepArgs { WDesc w[10]; };

__global__ __launch_bounds__(256) void wprep_kernel(WPrepArgs args)
{
    WDesc d = args.w[blockIdx.z];
    int k0 = blockIdx.x * 32;
    int n0 = blockIdx.y * 32;
    if (k0 >= d.K || n0 >= d.N) return;
    __shared__ unsigned short t[32][33];
    int tx = threadIdx.x & 31, ty = threadIdx.x >> 5;
    #pragma unroll
    for (int i = 0; i < 4; ++i) {
        int kk = ty + i * 8;
        t[kk][tx] = f2bf(d.src[(size_t)(k0 + kk) * d.N + n0 + tx]);
    }
    __syncthreads();
    #pragma unroll
    for (int i = 0; i < 4; ++i) {
        int nn = ty + i * 8;
        d.dst[(size_t)(n0 + nn) * d.K + k0 + tx] = t[tx][nn];
    }
}

// ---------------------------------------------------------------------------
// Bias concat: bqkv[768] = bq|bk|bv ; boffaw[384] = boff|baw
// ---------------------------------------------------------------------------
__global__ __launch_bounds__(256) void bias_concat_kernel(
    const float* __restrict__ bq, const float* __restrict__ bk,
    const float* __restrict__ bv, const float* __restrict__ boff,
    const float* __restrict__ baw, float* __restrict__ bqkv,
    float* __restrict__ boffaw)
{
    int t = blockIdx.x * 256 + threadIdx.x;
    if (t < 256)       bqkv[t] = bq[t];
    else if (t < 512)  bqkv[t] = bk[t - 256];
    else if (t < 768)  bqkv[t] = bv[t - 512];
    if (t < 256)       boffaw[t] = boff[t];
    else if (t < 384)  boffaw[t] = baw[t - 256];
}

// ---------------------------------------------------------------------------
// bf16 MFMA GEMM: C[M,N] = bf16(A [+A2]) @ B + bias.
// BM=128, BN=128, BK=32; 256 threads = 4 waves (2x2), wave 64x64, 4x4 frags.
// flags: RELU | OBF (bf16 out via LDS repack) | SWAP (grid.x=cols) |
// QKV (drop A2 for col0>=512).
// ---------------------------------------------------------------------------
__global__ __launch_bounds__(256) void gemm_bf16_kernel(
    const float* __restrict__ A, const float* __restrict__ A2,
    const unsigned short* __restrict__ BT, const float* __restrict__ bias,
    void* __restrict__ Cout, int M, int N, int K, int flags)
{
    __shared__ uint4 SMEM[1088];   // staging 16KB (A 8K + B 8K); repack 17408B
    uint4* As4 = SMEM;             // [128*4]
    uint4* Bs4 = SMEM + 512;       // [128*4]

    const int tid = threadIdx.x;
    const int lane = tid & 63;
    const int wave = tid >> 6;
    const int wm = wave >> 1;
    const int wn = wave & 1;
    const int row0 = (flags & FLAG_SWAP ? blockIdx.y : blockIdx.x) * 128;
    const int col0 = (flags & FLAG_SWAP ? blockIdx.x : blockIdx.y) * 128;
    if ((flags & FLAG_QKV) && col0 >= 512) A2 = nullptr;

    f32x4 acc[4][4];
    #pragma unroll
    for (int i = 0; i < 4; ++i)
        #pragma unroll
        for (int j = 0; j < 4; ++j)
            acc[i][j] = {0.f, 0.f, 0.f, 0.f};

    const int ar  = tid >> 1;          // A/B stage row 0..127
    const int ah  = (tid & 1) * 16;    // A float col offset
    const int acb = (tid & 1) * 2;     // chunk base
    const int agr = row0 + ar;
    const bool aok = agr < M;
    const int bgr = col0 + ar;         // B row (output col), always < N

    const int lr = lane & 15;
    const int lc = lane >> 4;

    const bf16x8* Asb = (const bf16x8*)As4;
    const bf16x8* Bsb = (const bf16x8*)Bs4;

    for (int k0 = 0; k0 < K; k0 += 32) {
        float fl[16];
        #pragma unroll
        for (int j = 0; j < 16; ++j) fl[j] = 0.f;
        if (aok) {
            const float* ap = A + (size_t)agr * K + k0 + ah;
            #pragma unroll
            for (int j = 0; j < 4; ++j) {
                float4 t = *(const float4*)(ap + j * 4);
                fl[j*4+0] = t.x; fl[j*4+1] = t.y; fl[j*4+2] = t.z; fl[j*4+3] = t.w;
            }
            if (A2) {
                const float* ap2 = A2 + (size_t)agr * K + k0 + ah;
                #pragma unroll
                for (int j = 0; j < 4; ++j) {
                    float4 t = *(const float4*)(ap2 + j * 4);
                    fl[j*4+0] += t.x; fl[j*4+1] += t.y; fl[j*4+2] += t.z; fl[j*4+3] += t.w;
                }
            }
        }
        uint4 bq0 = *(const uint4*)(BT + (size_t)bgr * K + k0 + (acb + 0) * 8);
        uint4 bq1 = *(const uint4*)(BT + (size_t)bgr * K + k0 + (acb + 1) * 8);

        __syncthreads();
        union { unsigned short us[8]; uint4 q; } pk0, pk1;
        #pragma unroll
        for (int j = 0; j < 8; ++j) { pk0.us[j] = f2bf(fl[j]); pk1.us[j] = f2bf(fl[8 + j]); }
        As4[ar * 4 + ((acb + 0) ^ SW(ar))] = pk0.q;
        As4[ar * 4 + ((acb + 1) ^ SW(ar))] = pk1.q;
        Bs4[ar * 4 + ((acb + 0) ^ SW(ar))] = bq0;
        Bs4[ar * 4 + ((acb + 1) ^ SW(ar))] = bq1;
        __syncthreads();

        bf16x8 af[4], bfr[4];
        #pragma unroll
        for (int mi = 0; mi < 4; ++mi) {
            int r = wm * 64 + mi * 16 + lr;
            af[mi] = Asb[r * 4 + (lc ^ SW(r))];
        }
        #pragma unroll
        for (int ni = 0; ni < 4; ++ni) {
            int r = wn * 64 + ni * 16 + lr;
            bfr[ni] = Bsb[r * 4 + (lc ^ SW(r))];
        }
        #pragma unroll
        for (int mi = 0; mi < 4; ++mi)
            #pragma unroll
            for (int ni = 0; ni < 4; ++ni)
                acc[mi][ni] = __builtin_amdgcn_mfma_f32_16x16x32_bf16(
                    af[mi], bfr[ni], acc[mi][ni], 0, 0, 0);
    }

    const int relu = flags & FLAG_RELU;
    if (!(flags & FLAG_OBF)) {
        float* C = (float*)Cout;
        #pragma unroll
        for (int ni = 0; ni < 4; ++ni) {
            int col = col0 + wn * 64 + ni * 16 + lr;
            if (col >= N) continue;
            float bval = bias[col];
            #pragma unroll
            for (int mi = 0; mi < 4; ++mi) {
                #pragma unroll
                for (int rg = 0; rg < 4; ++rg) {
                    int row = row0 + wm * 64 + mi * 16 + lc * 4 + rg;
                    if (row < M) {
                        float o = acc[mi][ni][rg] + bval;
                        if (relu) o = fmaxf(o, 0.f);
                        C[(size_t)row * N + col] = o;
                    }
                }
            }
        }
    } else {
        // bf16 epilogue via LDS repack -> 64B/lane coalesced stores
        unsigned short* RP = (unsigned short*)SMEM;  // [64][136] shorts
        unsigned short* C = (unsigned short*)Cout;
        float bval[4];
        #pragma unroll
        for (int ni = 0; ni < 4; ++ni) {
            int col = col0 + wn * 64 + ni * 16 + lr;
            bval[ni] = (col < N) ? bias[col] : 0.f;
        }
        #pragma unroll
        for (int h2 = 0; h2 < 2; ++h2) {
            __syncthreads();
            if (wm == h2) {
                #pragma unroll
                for (int ni = 0; ni < 4; ++ni) {
                    int colL = wn * 64 + ni * 16 + lr;
                    #pragma unroll
                    for (int mi = 0; mi < 4; ++mi) {
                        #pragma unroll
                        for (int rg = 0; rg < 4; ++rg) {
                            int rowL = mi * 16 + lc * 4 + rg;
                            float o = acc[mi][ni][rg] + bval[ni];
                            if (relu) o = fmaxf(o, 0.f);
                            RP[rowL * 136 + colL] = f2bf(o);
                        }
                    }
                }
            }
            __syncthreads();
            {
                int r = tid >> 2;            // 0..63
                int c = tid & 3;             // 0..3
                int grow = row0 + h2 * 64 + r;
                if (grow < M) {
                    #pragma unroll
                    for (int j = 0; j < 4; ++j) {
                        int gcol = col0 + c * 32 + j * 8;
                        if (gcol < N) {
                            uint4 vq = *(const uint4*)&RP[r * 136 + c * 32 + j * 8];
                            *(uint4*)(C + (size_t)grow * N + gcol) = vq;
                        }
                    }
                }
            }
        }
    }
}

// ---------------------------------------------------------------------------
// MFMA flash self-attention over fused QKV buffer [M][768]
// (q at +0, k at +256, v at +512 per row)
// ---------------------------------------------------------------------------
#define QKVS 768
__global__ __launch_bounds__(256) void attn_mfma_kernel(
    const float* __restrict__ qkv, float* __restrict__ out)
{
    __shared__ uint4 Kls[64 * 4];
    __shared__ uint4 Vtls[32 * 8];

    const int tid = threadIdx.x;
    const int lane = tid & 63;
    const int wave = tid >> 6;
    const int qcol = lane & 15;
    const int g = lane >> 4;
    const int bh = blockIdx.x;
    const int h = bh & 7, b = bh >> 3;
    const int qg = blockIdx.y * 64 + wave * 16 + qcol;
    const int qc = qg < NQ ? qg : NQ - 1;

    bf16x8 qf;
    {
        const float sc = 0.17677669529663687f;
        const float* qp = qkv + ((size_t)(b * NQ + qc)) * QKVS + h * 32 + g * 8;
        float4 f0 = *(const float4*)qp;
        float4 f1 = *(const float4*)(qp + 4);
        union { unsigned short us[8]; bf16x8 v8; } pk;
        pk.us[0] = f2bf(f0.x * sc); pk.us[1] = f2bf(f0.y * sc);
        pk.us[2] = f2bf(f0.z * sc); pk.us[3] = f2bf(f0.w * sc);
        pk.us[4] = f2bf(f1.x * sc); pk.us[5] = f2bf(f1.y * sc);
        pk.us[6] = f2bf(f1.z * sc); pk.us[7] = f2bf(f1.w * sc);
        qf = pk.v8;
    }

    float mrun = -3.0e38f, lrun = 0.f;
    f32x4 oacc[2];
    oacc[0] = {0.f, 0.f, 0.f, 0.f};
    oacc[1] = {0.f, 0.f, 0.f, 0.f};
    const f32x4 zacc = {0.f, 0.f, 0.f, 0.f};

    const int kidx = tid >> 2, kdc = tid & 3;
    const int vkp = tid >> 3, vdc = tid & 7;
    const bf16x8* Kb = (const bf16x8*)Kls;
    const bf16x8* Vb = (const bf16x8*)Vtls;
    unsigned int* V32 = (unsigned int*)Vtls;

    for (int jb = 0; jb < NQ; jb += 64) {
        __syncthreads();
        {
            int gk = jb + kidx;
            float4 f0 = make_float4(0.f, 0.f, 0.f, 0.f), f1 = f0;
            if (gk < NQ) {
                const float* kp = qkv + ((size_t)(b * NQ + gk)) * QKVS + 256 + h * 32 + kdc * 8;
                f0 = *(const float4*)kp;
                f1 = *(const float4*)(kp + 4);
            }
            union { unsigned short us[8]; uint4 u; } pk;
            pk.us[0] = f2bf(f0.x); pk.us[1] = f2bf(f0.y);
            pk.us[2] = f2bf(f0.z); pk.us[3] = f2bf(f0.w);
            pk.us[4] = f2bf(f1.x); pk.us[5] = f2bf(f1.y);
            pk.us[6] = f2bf(f1.z); pk.us[7] = f2bf(f1.w);
            Kls[kidx * 4 + (kdc ^ ((kidx >> 1) & 3))] = pk.u;
        }
        {
            int k0g = jb + 2 * vkp;
            float4 v0 = make_float4(0.f, 0.f, 0.f, 0.f), v1 = v0;
            if (k0g < NQ)
                v0 = *(const float4*)(qkv + ((size_t)(b * NQ + k0g)) * QKVS + 512 + h * 32 + vdc * 4);
            if (k0g + 1 < NQ)
                v1 = *(const float4*)(qkv + ((size_t)(b * NQ + k0g + 1)) * QKVS + 512 + h * 32 + vdc * 4);
            float a0[4] = {v0.x, v0.y, v0.z, v0.w};
            float a1[4] = {v1.x, v1.y, v1.z, v1.w};
            #pragma unroll
            for (int j = 0; j < 4; ++j) {
                int d = vdc * 4 + j;
                unsigned int val = (unsigned int)f2bf(a0[j]) | ((unsigned int)f2bf(a1[j]) << 16);
                V32[d * 32 + ((vkp >> 2) ^ (d & 7)) * 4 + (vkp & 3)] = val;
            }
        }
        __syncthreads();

        f32x4 sacc[4];
        #pragma unroll
        for (int kt = 0; kt < 4; ++kt) {
            int key = kt * 16 + qcol;
            bf16x8 kf = Kb[key * 4 + (g ^ ((key >> 1) & 3))];
            sacc[kt] = __builtin_amdgcn_mfma_f32_16x16x32_bf16(kf, qf, zacc, 0, 0, 0);
        }
        if (jb + 64 > NQ) {
            #pragma unroll
            for (int kt = 0; kt < 4; ++kt)
                #pragma unroll
                for (int r = 0; r < 4; ++r)
                    if (jb + kt * 16 + 4 * g + r >= NQ) sacc[kt][r] = -3.0e38f;
        }

        float mloc = -3.0e38f;
        #pragma unroll
        for (int kt = 0; kt < 4; ++kt)
            #pragma unroll
            for (int r = 0; r < 4; ++r)
                mloc = fmaxf(mloc, sacc[kt][r]);
        mloc = fmaxf(mloc, __shfl_xor(mloc, 16));
        mloc = fmaxf(mloc, __shfl_xor(mloc, 32));
        float mnew = fmaxf(mrun, mloc);
        float corr = __expf(mrun - mnew);
        mrun = mnew;

        float lloc = 0.f;
        unsigned int pk2[4][2];
        #pragma unroll
        for (int kt = 0; kt < 4; ++kt) {
            float p0 = __expf(sacc[kt][0] - mnew);
            float p1 = __expf(sacc[kt][1] - mnew);
            float p2 = __expf(sacc[kt][2] - mnew);
            float p3 = __expf(sacc[kt][3] - mnew);
            lloc += p0 + p1 + p2 + p3;
            pk2[kt][0] = (unsigned int)f2bf(p0) | ((unsigned int)f2bf(p1) << 16);
            pk2[kt][1] = (unsigned int)f2bf(p2) | ((unsigned int)f2bf(p3) << 16);
        }
        lloc += __shfl_xor(lloc, 16);
        lloc += __shfl_xor(lloc, 32);
        lrun = lrun * corr + lloc;
        #pragma unroll
        for (int ni = 0; ni < 2; ++ni)
            #pragma unroll
            for (int r = 0; r < 4; ++r)
                oacc[ni][r] *= corr;

        const int s0 = qcol + 32 * (g & 1);
        const bool hi = (g >> 1) != 0;
        #pragma unroll
        for (int tp = 0; tp < 2; ++tp) {
            int A0 = (int)pk2[2 * tp][0], A1 = (int)pk2[2 * tp][1];
            int B0 = (int)pk2[2 * tp + 1][0], B1 = (int)pk2[2 * tp + 1][1];
            int a0 = __shfl(A0, s0),      a1 = __shfl(A1, s0);
            int b0 = __shfl(B0, s0),      b1 = __shfl(B1, s0);
            int a2 = __shfl(A0, s0 + 16), a3 = __shfl(A1, s0 + 16);
            int b2 = __shfl(B0, s0 + 16), b3 = __shfl(B1, s0 + 16);
            union { unsigned int u[4]; bf16x8 v8; } pf;
            pf.u[0] = hi ? (unsigned int)b0 : (unsigned int)a0;
            pf.u[1] = hi ? (unsigned int)b1 : (unsigned int)a1;
            pf.u[2] = hi ? (unsigned int)b2 : (unsigned int)a2;
            pf.u[3] = hi ? (unsigned int)b3 : (unsigned int)a3;
            #pragma unroll
            for (int ni = 0; ni < 2; ++ni) {
                int d = ni * 16 + qcol;
                bf16x8 vf = Vb[d * 8 + ((4 * tp + g) ^ (d & 7))];
                oacc[ni] = __builtin_amdgcn_mfma_f32_16x16x32_bf16(vf, pf.v8, oacc[ni], 0, 0, 0);
            }
        }
    }

    if (qg < NQ) {
        float inv = 1.f / lrun;
        float* op = out + ((size_t)(b * NQ + qg)) * DM + h * 32;
        float4 o0, o1;
        o0.x = oacc[0][0] * inv; o0.y = oacc[0][1] * inv;
        o0.z = oacc[0][2] * inv; o0.w = oacc[0][3] * inv;
        o1.x = oacc[1][0] * inv; o1.y = oacc[1][1] * inv;
        o1.z = oacc[1][2] * inv; o1.w = oacc[1][3] * inv;
        *(float4*)(op + 4 * g) = o0;
        *(float4*)(op + 16 + 4 * g) = o1;
    }
}

// ---------------------------------------------------------------------------
// aw softmax over fused offaw buffer [M][384]; logits at +256 + h*16
// ---------------------------------------------------------------------------
__global__ __launch_bounds__(256) void aw_softmax_kernel(float* __restrict__ offaw)
{
    int t = blockIdx.x * 256 + threadIdx.x;
    if (t >= BS * NQ * 8) return;
    int row = t >> 3, h = t & 7;
    float* p = offaw + (size_t)row * 384 + 256 + h * 16;
    float vals[16];
    #pragma unroll
    for (int i = 0; i < 4; ++i) {
        float4 f = *(const float4*)(p + i * 4);
        vals[4 * i + 0] = f.x; vals[4 * i + 1] = f.y;
        vals[4 * i + 2] = f.z; vals[4 * i + 3] = f.w;
    }
    float mx = vals[0];
    #pragma unroll
    for (int i = 1; i < 16; ++i) mx = fmaxf(mx, vals[i]);
    float sum = 0.f;
    #pragma unroll
    for (int i = 0; i < 16; ++i) { vals[i] = __expf(vals[i] - mx); sum += vals[i]; }
    float inv = 1.f / sum;
    #pragma unroll
    for (int i = 0; i < 4; ++i) {
        float4 f;
        f.x = vals[4 * i + 0] * inv; f.y = vals[4 * i + 1] * inv;
        f.z = vals[4 * i + 2] * inv; f.w = vals[4 * i + 3] * inv;
        *(float4*)(p + i * 4) = f;
    }
}

// ---------------------------------------------------------------------------
// Deformable sampling over bf16 value table; fused offaw [M][384]
// ---------------------------------------------------------------------------
__global__ __launch_bounds__(256) void deform_kernel(
    const unsigned short* __restrict__ value, const float* __restrict__ offaw,
    const float* __restrict__ rbbox, float* __restrict__ dout)
{
    int t = blockIdx.x * 256 + threadIdx.x;
    if (t >= BS * NQ * 64) return;
    int c = t & 7;
    int h = (t >> 3) & 7;
    int bq = t >> 6;
    int b = bq / NQ;

    const int Hs[4]     = {100, 50, 25, 13};
    const int Wsz[4]    = {100, 50, 25, 13};
    const int Starts[4] = {0, 10000, 12500, 13125};

    float4 rb = *(const float4*)(rbbox + (size_t)bq * 4);
    const float* offp = offaw + (size_t)bq * 384 + h * 32;
    const float* awp  = offaw + (size_t)bq * 384 + 256 + h * 16;
    const unsigned short* vb = value + ((size_t)b * LEN_V) * 256 + h * 32 + c * 4;

    float4 acc = make_float4(0.f, 0.f, 0.f, 0.f);
    #pragma unroll
    for (int l = 0; l < 4; ++l) {
        const int H = Hs[l], W = Wsz[l], st = Starts[l];
        #pragma unroll
        for (int p = 0; p < 4; ++p) {
            float ox = offp[l * 8 + p * 2 + 0];
            float oy = offp[l * 8 + p * 2 + 1];
            float a_w = awp[l * 4 + p];
            float xx = (rb.x + ox * 0.125f * rb.z) * W - 0.5f;
            float yy = (rb.y + oy * 0.125f * rb.w) * H - 0.5f;
            float x0f = floorf(xx), y0f = floorf(yy);
            float fx = xx - x0f, fy = yy - y0f;
            int x0 = (int)x0f, y0 = (int)y0f;
            #pragma unroll
            for (int dy = 0; dy < 2; ++dy) {
                int yi = y0 + dy;
                float wy = dy ? fy : (1.f - fy);
                bool vy = (yi >= 0) && (yi < H);
                int yc = min(max(yi, 0), H - 1);
                #pragma unroll
                for (int dx = 0; dx < 2; ++dx) {
                    int xi = x0 + dx;
                    float wx = dx ? fx : (1.f - fx);
                    bool vx = (xi >= 0) && (xi < W);
                    int xc = min(max(xi, 0), W - 1);
                    float wgt = a_w * wy * wx * ((vx && vy) ? 1.f : 0.f);
                    ushort4 gv = *(const ushort4*)(vb + (size_t)(st + yc * W + xc) * 256);
                    acc.x += wgt * bf2f(gv.x); acc.y += wgt * bf2f(gv.y);
                    acc.z += wgt * bf2f(gv.z); acc.w += wgt * bf2f(gv.w);
                }
            }
        }
    }
    *(float4*)(dout + (size_t)bq * 256 + h * 32 + c * 4) = acc;
}

// ---------------------------------------------------------------------------
__global__ __launch_bounds__(256) void ln_kernel(
    const float* __restrict__ x, const float* __restrict__ dx,
    const float* __restrict__ g, const float* __restrict__ bt,
    float* __restrict__ out, int rows)
{
    int row = blockIdx.x * 4 + (threadIdx.x >> 6);
    if (row >= rows) return;
    int lane = threadIdx.x & 63;
    size_t base = (size_t)row * 256 + lane * 4;
    float4 xv = *(const float4*)(x + base);
    float4 dv = *(const float4*)(dx + base);
    float a0 = xv.x + dv.x, a1 = xv.y + dv.y, a2 = xv.z + dv.z, a3 = xv.w + dv.w;
    float s = a0 + a1 + a2 + a3;
    float s2 = a0 * a0 + a1 * a1 + a2 * a2 + a3 * a3;
    #pragma unroll
    for (int o = 32; o; o >>= 1) {
        s += __shfl_xor(s, o);
        s2 += __shfl_xor(s2, o);
    }
    float mean = s * (1.f / 256.f);
    float var = s2 * (1.f / 256.f) - mean * mean;
    float inv = rsqrtf(var + 1e-5f);
    float4 gv = *(const float4*)(g + lane * 4);
    float4 bv = *(const float4*)(bt + lane * 4);
    float4 r;
    r.x = (a0 - mean) * inv * gv.x + bv.x;
    r.y = (a1 - mean) * inv * gv.y + bv.y;
    r.z = (a2 - mean) * inv * gv.z + bv.z;
    r.w = (a3 - mean) * inv * gv.w + bv.w;
    *(float4*)(out + base) = r;
}

// ---------------------------------------------------------------------------
extern "C" void kernel_launch(void* const* d_in, const int* in_sizes, int n_in,
                              void* d_out, int out_size, void* d_ws, size_t ws_size,
                              hipStream_t stream)
{
    const float* embed = (const float*)d_in[0];
    const float* rbbox = (const float*)d_in[1];
    const float* feats = (const float*)d_in[2];
    const float* qpos  = (const float*)d_in[3];
    const float* Wq = (const float*)d_in[4];  const float* bq = (const float*)d_in[5];
    const float* Wk = (const float*)d_in[6];  const float* bk = (const float*)d_in[7];
    const float* Wv = (const float*)d_in[8];  const float* bv = (const float*)d_in[9];
    const float* Wo = (const float*)d_in[10]; const float* bo = (const float*)d_in[11];
    const float* g1 = (const float*)d_in[12]; const float* b1 = (const float*)d_in[13];
    const float* Wval = (const float*)d_in[14]; const float* bval = (const float*)d_in[15];
    const float* Woff = (const float*)d_in[16]; const float* boff = (const float*)d_in[17];
    const float* Waw  = (const float*)d_in[18]; const float* baw  = (const float*)d_in[19];
    const float* Wop  = (const float*)d_in[20]; const float* bop  = (const float*)d_in[21];
    const float* g2 = (const float*)d_in[22]; const float* b2 = (const float*)d_in[23];
    const float* W1 = (const float*)d_in[24]; const float* bf1 = (const float*)d_in[25];
    const float* W2 = (const float*)d_in[26]; const float* bf2 = (const float*)d_in[27];
    const float* g3 = (const float*)d_in[28]; const float* b3 = (const float*)d_in[29];

    const int M = BS * NQ;                 // 7200
    const int MV = BS * LEN_V;             // 106352
    const size_t E = (size_t)M * DM;       // 1,843,200 floats
    const size_t VAL = (size_t)MV * DM;    // value region (floats)

    float* ws = (float*)d_ws;
    float* valueb = ws;                    // bf16 value table (54.5 MB of region)
    float* qkvreg = ws + VAL;              // 3E floats [M][768]
    float* attb   = qkvreg + 3 * E;        // E
    float* e1b    = attb + E;              // E
    unsigned short* wbase = (unsigned short*)(e1b + E);
    unsigned short* wqkv_t   = wbase;                     // 768*256
    unsigned short* wo_t     = wbase + 196608;            // 256*256
    unsigned short* wval_t   = wbase + 262144;            // 256*256
    unsigned short* woffaw_t = wbase + 327680;            // 384*256
    unsigned short* wop_t    = wbase + 425984;            // 256*256
    unsigned short* w1_t     = wbase + 491520;            // 1024*256
    unsigned short* w2_t     = wbase + 753664;            // 256*1024
    float* bqkv   = (float*)(wbase + 1015808);            // 768
    float* boffaw = bqkv + 768;                           // 384

    unsigned short* valuebf = (unsigned short*)valueb;
    float* sab    = qkvreg;            // Wo out (qkv dead after attn)
    float* offawb = qkvreg + E;        // [M][384], after LN1
    float* doutb  = attb;              // deform out (attb dead after Wo)
    float* cab    = qkvreg;            // Wop out (sab dead after LN1)
    float* e2b    = qkvreg + 2 * E;    // LN2 out (offaw dead after deform)
    float* ffhb   = valueb;            // FFN hidden (value dead after deform)
    float* ffb    = attb;              // FFN out (dout dead after Wop)

    dim3 blk(256);
    // swapped grid: x = col-blocks of 128
    auto gs = [](int m, int n) { return dim3((n + 127) / 128, (m + 127) / 128); };

    // 0: weight + bias prep
    {
        WPrepArgs a;
        a.w[0] = {Wq,   wqkv_t,                 256, 256};
        a.w[1] = {Wk,   wqkv_t + 256 * 256,     256, 256};
        a.w[2] = {Wv,   wqkv_t + 512 * 256,     256, 256};
        a.w[3] = {Wo,   wo_t,                   256, 256};
        a.w[4] = {Wval, wval_t,                 256, 256};
        a.w[5] = {Woff, woffaw_t,               256, 256};
        a.w[6] = {Waw,  woffaw_t + 256 * 256,   256, 128};
        a.w[7] = {Wop,  wop_t,                  256, 256};
        a.w[8] = {W1,   w1_t,                   256, 1024};
        a.w[9] = {W2,   w2_t,                   1024, 256};
        wprep_kernel<<<dim3(32, 32, 10), blk, 0, stream>>>(a);
        bias_concat_kernel<<<dim3(3), blk, 0, stream>>>(bq, bk, bv, boff, baw, bqkv, boffaw);
    }

    // 1: fused QKV projection (N=768; v columns skip +qpos)
    gemm_bf16_kernel<<<gs(M, 768), blk, 0, stream>>>(embed, qpos, wqkv_t, bqkv, qkvreg, M, 768, 256, FLAG_SWAP | FLAG_QKV);
    // 2: self-attention (MFMA flash)
    attn_mfma_kernel<<<dim3(BS * 8, (NQ + 63) / 64), blk, 0, stream>>>(qkvreg, attb);
    // 3: output projection
    gemm_bf16_kernel<<<gs(M, 256), blk, 0, stream>>>(attb, nullptr, wo_t, bo, sab, M, 256, 256, FLAG_SWAP);
    // 4: LN1
    ln_kernel<<<dim3((M + 3) / 4), blk, 0, stream>>>(embed, sab, g1, b1, e1b, M);
    // 5: value projection (big GEMM) -> bf16 via LDS repack
    gemm_bf16_kernel<<<gs(MV, 256), blk, 0, stream>>>(feats, nullptr, wval_t, bval, valuebf, MV, 256, 256, FLAG_SWAP | FLAG_OBF);
    // 6: fused offsets + aw logits (query = e1 + qpos)
    gemm_bf16_kernel<<<gs(M, 384), blk, 0, stream>>>(e1b, qpos, woffaw_t, boffaw, offawb, M, 384, 256, FLAG_SWAP);
    // 7: softmax over 16
    aw_softmax_kernel<<<dim3((BS * NQ * 8 + 255) / 256), blk, 0, stream>>>(offawb);
    // 8: deformable sampling (bf16 gathers)
    deform_kernel<<<dim3((BS * NQ * 64 + 255) / 256), blk, 0, stream>>>(valuebf, offawb, rbbox, doutb);
    // 9: output projection of deformable attention
    gemm_bf16_kernel<<<gs(M, 256), blk, 0, stream>>>(doutb, nullptr, wop_t, bop, cab, M, 256, 256, FLAG_SWAP);
    // 10: LN2
    ln_kernel<<<dim3((M + 3) / 4), blk, 0, stream>>>(e1b, cab, g2, b2, e2b, M);
    // 11-12: FFN (relu fused in FFN1)
    gemm_bf16_kernel<<<gs(M, 1024), blk, 0, stream>>>(e2b, nullptr, w1_t, bf1, ffhb, M, 1024, 256, FLAG_SWAP | FLAG_RELU);
    gemm_bf16_kernel<<<gs(M, 256), blk, 0, stream>>>(ffhb, nullptr, w2_t, bf2, ffb, M, 256, 1024, FLAG_SWAP);
    // 13: LN3 -> out
    ln_kernel<<<dim3((M + 3) / 4), blk, 0, stream>>>(e2b, ffb, g3, b3, (float*)d_out, M);
}